// Round 16
// baseline (198.570 us; speedup 1.0000x reference)
//
#include <hip/hip_runtime.h>
#include <hip/hip_bf16.h>

// InfiniteNeuralNetwork: the scan state stays row-constant, so
//   p[j] = (1/D) * prod_{d,k} cos^2(inf_w[d,j,k])
// and each infinite layer is just tanh(x @ cls_w + cls_b + p).
// Network = 6 GEMMs [2048x2048x2048] with fused epilogues.
// R14 (best, 184.6us): BM128/BN64/BK64, 2 blocks/CU, XOR-swizzle,
//   counted vmcnt, 22us/GEMM == LDS-port floor (72KB/step @ 85B/cy).
// R15: 64x64 K-split wave tiles REGRESSED (1 block/CU convoy).
// R16: B out of LDS: weights stored FRAGMENT-PACKED (per (ncol64,ktile)
//   8KB chunk, lane-ordered) -> B loads are 4x1KB contiguous
//   global->reg (fixes R10's stride problem). A stays global_load_lds,
//   4 bufs, ONE barrier/step. LDS/step 72->48KB.

#define DD 2048
#define DEPTH 9

#define BM 128
#define BN 64
#define BK 64
#define NT (DD / BK)     // 32 K-tiles
#define ABUF (BM * BK)   // 8192 shorts = 16KB
#define DDe ((size_t)DD * DD)

typedef __attribute__((ext_vector_type(8))) short short8;
typedef __attribute__((ext_vector_type(4))) float f32x4;

__device__ __forceinline__ unsigned short f2bf(float f) {
  unsigned u = __float_as_uint(f);
  u += 0x7FFFu + ((u >> 16) & 1u);   // round-to-nearest-even
  return (unsigned short)(u >> 16);
}

// Packed-B layout: for weight w[k][n] (f32 [K][N]), B = w^T as fragments.
// chunk index c in tile (nc, kt): q = c>>6 (0..7), l = c&63.
//   n = nc*64 + (q>>2)*32 + ((q>>1)&1)*16 + (l&15)
//   k = kt*64 + (q&1)*32 + (l>>4)*8 + e     (e = 0..7)
//   packed[((nc*NT + kt)*8 + q)*512 + l*8 + e] = bf16(w[k][n])
// Loader (wave wc, tile T, frag j = nt*2+ks): q = wc*4 + j; lane l reads
// 16B at ((nc*NT+T)*8+q)*512 + l*8  -> contiguous 1KB per load. [R16]

// ---------------- fused prep kernel ----------------
// blocks [0,2048): pack-transpose w0,w1 (64x64 tiles, 1024 per weight)
// blocks [2048,6144): cvt x -> bf16
// blocks [6144,6160): padd for both infinite layers
__global__ __launch_bounds__(256) void prep_kernel(
    const float* __restrict__ w0, const float* __restrict__ w1,
    unsigned short* __restrict__ wts, const float* __restrict__ x,
    unsigned short* __restrict__ xb, const float* __restrict__ infw1,
    const float* __restrict__ infw2, const float* __restrict__ clsb1,
    const float* __restrict__ clsb2, float* __restrict__ padd1,
    float* __restrict__ padd2) {
  int b = blockIdx.x;
  int tid = threadIdx.x;
  if (b < 2048) {
    __shared__ float ft[64 * 65];
    int z = b >> 10;              // 0: w0, 1: w1
    int tau = b & 1023;
    int nc = tau & 31, kt = tau >> 5;
    const float* src = z ? w1 : w0;
    unsigned short* dst = wts + (size_t)z * DDe;
#pragma unroll
    for (int it = 0; it < 4; ++it) {       // read 64 rows x 16 float4
      int idx = it * 256 + tid;
      int r = idx >> 4, c4 = (idx & 15) * 4;
      float4 v = *reinterpret_cast<const float4*>(
          &src[(size_t)(kt * 64 + r) * DD + nc * 64 + c4]);
      ft[r * 65 + c4 + 0] = v.x;
      ft[r * 65 + c4 + 1] = v.y;
      ft[r * 65 + c4 + 2] = v.z;
      ft[r * 65 + c4 + 3] = v.w;
    }
    __syncthreads();
#pragma unroll
    for (int it = 0; it < 2; ++it) {       // write 512 packed 16B chunks
      int c = it * 256 + tid;
      int q = c >> 6, l = c & 63;
      int kl0 = (q & 1) * 32 + (l >> 4) * 8;
      int nl = (q >> 2) * 32 + ((q >> 1) & 1) * 16 + (l & 15);
      short8 o;
#pragma unroll
      for (int e = 0; e < 8; ++e)
        o[e] = (short)f2bf(ft[(kl0 + e) * 65 + nl]);
      *reinterpret_cast<short8*>(
          &dst[(((size_t)nc * NT + kt) * 8 + q) * 512 + (size_t)l * 8]) = o;
    }
  } else if (b < 6144) {
    int i = (b - 2048) * 256 + tid;       // 1,048,576 float4 chunks
    float4 v = reinterpret_cast<const float4*>(x)[i];
    ushort4 o;
    o.x = f2bf(v.x); o.y = f2bf(v.y); o.z = f2bf(v.z); o.w = f2bf(v.w);
    reinterpret_cast<ushort4*>(xb)[i] = o;
  } else {
    int jj = (b - 6144) * 256 + tid;      // 0..4095
    int layer = jj >> 11;
    int j = jj & 2047;
    const float* inf_w = layer ? infw2 : infw1;
    const float* cls_b = layer ? clsb2 : clsb1;
    float* padd = layer ? padd2 : padd1;
    float prod = 1.0f;
#pragma unroll
    for (int d = 0; d < DEPTH; ++d) {
      const float* row = inf_w + ((size_t)d * DD + j) * DD;
      prod *= cosf(row[0]) * cosf(row[1]) * cosf(row[2]);
    }
    padd[j] = cls_b[j] + prod * prod * (1.0f / (float)DD);
  }
}

// ---------------- GEMM ----------------

__device__ __forceinline__ void gload_lds16(const unsigned short* g,
                                            unsigned short* l) {
  __builtin_amdgcn_global_load_lds(
      (const __attribute__((address_space(1))) void*)g,
      (__attribute__((address_space(3))) void*)l, 16, 0, 0);
}

#define MFMA_(A_, B_, C_) \
  __builtin_amdgcn_mfma_f32_16x16x32_bf16(A_, B_, C_, 0, 0, 0)

// B fragments for tile T -> register set S (literal). 4 x 1KB contiguous.
#define BLOAD(S, T) do {                                                   \
    const unsigned short* _p = Bpk + ((size_t)(T) * 8 + wc4) * 512 + lane * 8; \
    _Pragma("unroll")                                                      \
    for (int _j = 0; _j < 4; ++_j)                                         \
      breg##S[_j] = *reinterpret_cast<const short8*>(_p + _j * 512);       \
  } while (0)

// A fragments (8 ds_read_b128) + 16 MFMA. BUF/S literals.
#define COMPUTE(BUF, S) do {                                               \
    short8 _a[4][2];                                                       \
    _Pragma("unroll")                                                      \
    for (int _ks = 0; _ks < 2; ++_ks)                                      \
      _Pragma("unroll")                                                    \
      for (int _mt = 0; _mt < 4; ++_mt) {                                  \
        int _row = wr * 64 + _mt * 16 + lr;                                \
        int _slot = (_ks * 4 + lg) ^ ((_row >> 1) & 7);                    \
        _a[_mt][_ks] = *reinterpret_cast<const short8*>(                   \
            &As[(BUF) * ABUF + _row * BK + _slot * 8]);                    \
      }                                                                    \
    __builtin_amdgcn_s_setprio(1);                                         \
    _Pragma("unroll")                                                      \
    for (int _ks = 0; _ks < 2; ++_ks)                                      \
      _Pragma("unroll")                                                    \
      for (int _mt = 0; _mt < 4; ++_mt)                                    \
        _Pragma("unroll")                                                  \
        for (int _nt = 0; _nt < 2; ++_nt)                                  \
          acc[_mt][_nt] =                                                  \
              MFMA_(_a[_mt][_ks], breg##S[_nt * 2 + _ks], acc[_mt][_nt]);  \
    __builtin_amdgcn_s_setprio(0);                                         \
  } while (0)

// One step: wait (counted), barrier, issue B(t+2)+A(t+3), compute(t).
// Steady vmcnt(12) = {A(t+1), B(t+1), A(t+2)} in flight after B(t) done.
// One barrier suffices: stage target (t+3)&3 == (t-1)&3 was consumed by
// compute(t-1) before any wave reached this barrier (R9-verified scheme).
#define STEP(T, BUF, S, LS, WC, DOB, DOA) do {                             \
    if ((WC) == 12) asm volatile("s_waitcnt vmcnt(12)" ::: "memory");      \
    else if ((WC) == 8) asm volatile("s_waitcnt vmcnt(8)" ::: "memory");   \
    else asm volatile("s_waitcnt vmcnt(0)" ::: "memory");                  \
    __builtin_amdgcn_s_barrier();                                          \
    __builtin_amdgcn_sched_barrier(0);                                     \
    if (DOB) BLOAD(LS, (T) + 2);                                           \
    if (DOA) stageA(((T) + 3) & 3, (T) + 3);                               \
    COMPUTE(BUF, S);                                                       \
  } while (0)

// EPI: 0 = relu -> bf16, 1 = tanh -> bf16, 2 = relu -> f32
// A: [M][K] bf16 row-major. Bt: fragment-packed weight. bias: [N] f32.
// tsrc/tdst: optional pack-transpose tail (for a LATER gemm's weight).
template <int EPI>
__global__ __launch_bounds__(256, 2) void gemm_kernel(
    const unsigned short* __restrict__ A, const unsigned short* __restrict__ Bt,
    const float* __restrict__ bias, unsigned short* __restrict__ Cb,
    float* __restrict__ Cf, const float* __restrict__ tsrc,
    unsigned short* __restrict__ tdst) {
  const int N = DD, K = DD;
  // 64KB union: 4 A pipeline buffers (4x16KB) / epilogue f32 tile
  // (128*68*4 = 34816B) / tail pack tile (64*65*4 = 16.6KB).
  __shared__ __align__(16) unsigned char smem[65536];
  unsigned short* As = (unsigned short*)smem;   // 4 x 8192 elements

  int tid = threadIdx.x;
  int wid = tid >> 6, lane = tid & 63;
  int wr = wid >> 1, wc = wid & 1;   // wave grid 2x2, wave tile 64x32
  int wc4 = wc * 4;
  int lr = lane & 15;
  int lg = lane >> 4;

  // XCD-aware bijective swizzle over 512 blocks (512 % 8 == 0).
  int bid = blockIdx.x;
  int swz = (bid & 7) * 64 + (bid >> 3);
  int bcol = (swz & 31) * BN;   // 32 n-tiles
  int brow = (swz >> 5) * BM;   // 16 m-tiles

  const unsigned short* Abase = A + (size_t)brow * K;
  const unsigned short* Bpk = Bt + (size_t)(bcol >> 6) * NT * 8 * 512;

  // A staging (rule 21): LDS dest linear (wave-uniform base); source slot
  // pre-swizzled with the reader's involution slot' = slot ^ ((row>>1)&7).
  auto stageA = [&](int buf, int tile) {
    int kt = tile * BK;
#pragma unroll
    for (int r = 0; r < 4; ++r) {
      int chunk = r * 256 + tid;          // A: 128 rows x 8 slots = 1024
      int row = chunk >> 3;
      int sp = chunk & 7;
      int kof = (sp ^ ((row >> 1) & 7)) * 8;
      gload_lds16(Abase + (size_t)row * K + kt + kof,
                  As + buf * ABUF + (size_t)(r * 256 + wid * 64) * 8);
    }
  };

  f32x4 acc[4][2];
#pragma unroll
  for (int i = 0; i < 4; ++i)
#pragma unroll
    for (int j = 0; j < 2; ++j) acc[i][j] = f32x4{0.f, 0.f, 0.f, 0.f};

  short8 breg0[4], breg1[4], breg2[4];   // tile t -> set t%3

  // Prologue: A0 B0 A1 B1 A2 (20 outstanding; step-0 wait leaves 12).
  stageA(0, 0);
  BLOAD(0, 0);
  stageA(1, 1);
  BLOAD(1, 1);
  stageA(2, 2);

  // Steps 0..23 (period-12 literal pattern), then 24..31 tail.
#pragma unroll 1
  for (int i = 0; i < 2; ++i) {
    int t = 12 * i;
    STEP(t + 0, 0, 0, 2, 12, 1, 1);
    STEP(t + 1, 1, 1, 0, 12, 1, 1);
    STEP(t + 2, 2, 2, 1, 12, 1, 1);
    STEP(t + 3, 3, 0, 2, 12, 1, 1);
    STEP(t + 4, 0, 1, 0, 12, 1, 1);
    STEP(t + 5, 1, 2, 1, 12, 1, 1);
    STEP(t + 6, 2, 0, 2, 12, 1, 1);
    STEP(t + 7, 3, 1, 0, 12, 1, 1);
    STEP(t + 8, 0, 2, 1, 12, 1, 1);
    STEP(t + 9, 1, 0, 2, 12, 1, 1);
    STEP(t + 10, 2, 1, 0, 12, 1, 1);
    STEP(t + 11, 3, 2, 1, 12, 1, 1);
  }
  STEP(24, 0, 0, 2, 12, 1, 1);
  STEP(25, 1, 1, 0, 12, 1, 1);
  STEP(26, 2, 2, 1, 12, 1, 1);
  STEP(27, 3, 0, 2, 12, 1, 1);
  STEP(28, 0, 1, 0, 12, 1, 1);
  STEP(29, 1, 2, 1, 12, 1, 0);   // BLOAD(31) only
  STEP(30, 2, 0, 0, 8, 0, 0);    // vmcnt(8): {A31,B31} may remain
  STEP(31, 3, 1, 0, 0, 0, 0);    // vmcnt(0)

  // ---- epilogue: LDS-repack to coalesced 16B stores.
  // C/D layout col=lane&15, row=(lane>>4)*4+reg [m89-verified].
  {
    float* et = reinterpret_cast<float*>(smem);   // [128][68] f32
    __syncthreads();                              // pipeline LDS dead now
#pragma unroll
    for (int nt = 0; nt < 2; ++nt) {
      int colb = wc * 32 + nt * 16 + lr;
      float bs = bias[bcol + colb];
#pragma unroll
      for (int mt = 0; mt < 4; ++mt) {
#pragma unroll
        for (int i = 0; i < 4; ++i) {
          int rowb = wr * 64 + mt * 16 + lg * 4 + i;
          float v = acc[mt][nt][i] + bs;
          v = (EPI == 1) ? tanhf(v) : fmaxf(v, 0.0f);
          et[rowb * 68 + colb] = v;
        }
      }
    }
    __syncthreads();
#pragma unroll
    for (int it = 0; it < 4; ++it) {
      int chunk = it * 256 + tid;          // 1024 chunks of 8 elements
      int rowb = chunk >> 3;
      int c8 = (chunk & 7) * 8;
      float4 v0 = *reinterpret_cast<const float4*>(&et[rowb * 68 + c8]);
      float4 v1 = *reinterpret_cast<const float4*>(&et[rowb * 68 + c8 + 4]);
      size_t g = (size_t)(brow + rowb) * N + bcol + c8;
      if (EPI == 2) {
        *reinterpret_cast<float4*>(&Cf[g]) = v0;
        *reinterpret_cast<float4*>(&Cf[g + 4]) = v1;
      } else {
        uint4 o;
        o.x = (unsigned)f2bf(v0.x) | ((unsigned)f2bf(v0.y) << 16);
        o.y = (unsigned)f2bf(v0.z) | ((unsigned)f2bf(v0.w) << 16);
        o.z = (unsigned)f2bf(v1.x) | ((unsigned)f2bf(v1.y) << 16);
        o.w = (unsigned)f2bf(v1.z) | ((unsigned)f2bf(v1.w) << 16);
        *reinterpret_cast<uint4*>(&Cb[g]) = o;
      }
    }
  }

  // ---- pack-transpose tail: tsrc (f32 [K][N]) -> tdst fragment-packed,
  // for a LATER gemm's weight. 1024 64x64 tiles over 512 blocks.
  if (tsrc != nullptr) {
    float* ft = reinterpret_cast<float*>(smem);  // 64*65 f32 = 16.6KB
    __syncthreads();
#pragma unroll 1
    for (int t2 = 0; t2 < 2; ++t2) {
      int tau = bid * 2 + t2;
      int nc = tau & 31, kt = tau >> 5;
      if (t2) __syncthreads();
#pragma unroll
      for (int it = 0; it < 4; ++it) {     // read 64 rows x 16 float4
        int idx = it * 256 + tid;
        int r = idx >> 4, c4 = (idx & 15) * 4;
        float4 v = *reinterpret_cast<const float4*>(
            &tsrc[(size_t)(kt * 64 + r) * DD + nc * 64 + c4]);
        ft[r * 65 + c4 + 0] = v.x;
        ft[r * 65 + c4 + 1] = v.y;
        ft[r * 65 + c4 + 2] = v.z;
        ft[r * 65 + c4 + 3] = v.w;
      }
      __syncthreads();
#pragma unroll
      for (int it = 0; it < 2; ++it) {     // write 512 packed 16B chunks
        int c = it * 256 + tid;
        int q = c >> 6, l = c & 63;
        int kl0 = (q & 1) * 32 + (l >> 4) * 8;
        int nl = (q >> 2) * 32 + ((q >> 1) & 1) * 16 + (l & 15);
        short8 o;
#pragma unroll
        for (int e = 0; e < 8; ++e)
          o[e] = (short)f2bf(ft[(kl0 + e) * 65 + nl]);
        *reinterpret_cast<short8*>(
            &tdst[(((size_t)nc * NT + kt) * 8 + q) * 512 + (size_t)l * 8]) = o;
      }
    }
  }
}

// ---------------- launch ----------------

extern "C" void kernel_launch(void* const* d_in, const int* in_sizes, int n_in,
                              void* d_out, int out_size, void* d_ws,
                              size_t ws_size, hipStream_t stream) {
  const float* x     = (const float*)d_in[0];
  const float* w0    = (const float*)d_in[1];
  const float* b0    = (const float*)d_in[2];
  const float* w1    = (const float*)d_in[3];
  const float* b1    = (const float*)d_in[4];
  const float* infw1 = (const float*)d_in[5];
  const float* clsw1 = (const float*)d_in[6];
  const float* clsb1 = (const float*)d_in[7];
  const float* w2    = (const float*)d_in[8];
  const float* b2    = (const float*)d_in[9];
  const float* infw2 = (const float*)d_in[10];
  const float* clsw2 = (const float*)d_in[11];
  const float* clsb2 = (const float*)d_in[12];
  const float* w3    = (const float*)d_in[13];
  const float* b3    = (const float*)d_in[14];
  float* out = (float*)d_out;

  char* ws = (char*)d_ws;
  const size_t MB = 1ull << 20;
  unsigned short* buf0 = (unsigned short*)ws;              // 8 MB (x_bf16 / act)
  unsigned short* buf1 = (unsigned short*)(ws + 8 * MB);   // 8 MB (act)
  unsigned short* wts  = (unsigned short*)(ws + 16 * MB);  // 6 x 8 MB packed
  float* padd1 = (float*)(ws + 64 * MB);
  float* padd2 = padd1 + DD;

  prep_kernel<<<6160, 256, 0, stream>>>(w0, w1, wts, x, buf0, infw1, infw2,
                                        clsb1, clsb2, padd1, padd2);

  dim3 gg((DD / BM) * (DD / BN));  // 512 blocks -> 2 blocks/CU
  // GEMM_i tail-packs the weight consumed by GEMM_{i+2} (stream order
  // guarantees GEMM_i completes before GEMM_{i+1} starts).
  gemm_kernel<0><<<gg, 256, 0, stream>>>(buf0, wts + 0 * DDe, b0,    buf1,
                                         nullptr, clsw1, wts + 2 * DDe);
  gemm_kernel<0><<<gg, 256, 0, stream>>>(buf1, wts + 1 * DDe, b1,    buf0,
                                         nullptr, w2,    wts + 3 * DDe);
  gemm_kernel<1><<<gg, 256, 0, stream>>>(buf0, wts + 2 * DDe, padd1, buf1,
                                         nullptr, clsw2, wts + 4 * DDe);
  gemm_kernel<0><<<gg, 256, 0, stream>>>(buf1, wts + 3 * DDe, b2,    buf0,
                                         nullptr, w3,    wts + 5 * DDe);
  gemm_kernel<1><<<gg, 256, 0, stream>>>(buf0, wts + 4 * DDe, padd2, buf1,
                                         nullptr, nullptr, nullptr);
  gemm_kernel<2><<<gg, 256, 0, stream>>>(buf1, wts + 5 * DDe, b3,    nullptr,
                                         out, nullptr, nullptr);
}